// Round 3
// baseline (253.877 us; speedup 1.0000x reference)
//
#include <hip/hip_runtime.h>
#include <math.h>

// Problem constants (fixed by reference)
#define NN   10000
#define EE   160000
#define GG   128
#define HIDK 25
#define KROWS 32     // 25 MLP rows + 1 b2 row (k=25) + 6 zero-pad rows
#define DOUT 32
#define EPSBN 1e-5f

// ---------------- workspace layout (float offsets) ----------------
// zeroed region (one hipMemsetAsync):
#define OFF_CUR   0          // NN ints (scatter cursors), pad 10016
#define OFF_GSUM  10016      // G*32 = 4096
#define OFF_DEGC  14112      // NN ints, pad 10016
#define ZERO_FLOATS 24128
// non-zeroed:
#define OFF_MOP   24128      // 128*12 moment partials
#define OFF_W1F0  25664      // 80
#define OFF_B1F0  25744      // 32
#define OFF_W1F1  25776      // 80
#define OFF_B1F1  25856      // 32
#define OFF_ROW   25888      // NN+1 ints, pad 10016
#define OFF_SRC   35904      // E ints (csr src nodes)
#define OFF_EA    195904     // E*4 floats: edge_attr gathered into CSR slot order (float4-padded)
#define OFF_WB0   835904     // 32*16*32 = 16384
#define OFF_WB1   852288     // 32*32*32 = 32768
#define OFF_X1    885056     // N*32
#define TOTAL_FLOATS 1205056 // ~4.8 MB of d_ws

__device__ inline float wave_red(float v) {
    for (int off = 32; off; off >>= 1) v += __shfl_down(v, off);
    return v;
}

// ---- moments partials (128 blocks, atomic-free) + in-degree atomics, one pass
__global__ void k_momdeg(const float* __restrict__ ea, const int* __restrict__ ei,
                         float* __restrict__ mop, int* __restrict__ degc) {
    __shared__ float ls[4][9];
    float s[9];
#pragma unroll
    for (int j = 0; j < 9; j++) s[j] = 0.f;
    int t = threadIdx.x;
    for (int e = blockIdx.x * 256 + t; e < EE; e += 128 * 256) {
        float a0 = ea[3 * e], a1 = ea[3 * e + 1], a2 = ea[3 * e + 2];
        s[0] += a0; s[1] += a1; s[2] += a2;
        s[3] += a0 * a0; s[4] += a0 * a1; s[5] += a0 * a2;
        s[6] += a1 * a1; s[7] += a1 * a2; s[8] += a2 * a2;
        atomicAdd(degc + ei[EE + e], 1);
    }
    int w = t >> 6, lane = t & 63;
#pragma unroll
    for (int j = 0; j < 9; j++) {
        float r = wave_red(s[j]);
        if (lane == 0) ls[w][j] = r;
    }
    __syncthreads();
    if (t < 9) mop[blockIdx.x * 12 + t] = ls[0][t] + ls[1][t] + ls[2][t] + ls[3][t];
}

// ---- pack wbig[k][i4][o][c] = w2[k][i4*4+c][o]; row 25 = b2; rows >= 26 = 0
template <int DIN>
__device__ inline void wpack(int idx, const float* __restrict__ w2,
                             const float* __restrict__ b2, float* __restrict__ wbig) {
    int k = idx / (DIN * DOUT);
    int rem = idx - k * (DIN * DOUT);
    int i4 = rem / (4 * DOUT);
    int rem2 = rem - i4 * (4 * DOUT);
    int o = rem2 >> 2, c = rem2 & 3;
    int i = i4 * 4 + c;
    float v = 0.f;
    if (k < HIDK) v = w2[(k * DIN + i) * DOUT + o];
    else if (k == HIDK) v = b2[i * DOUT + o];
    wbig[idx] = v;
}

// ---- fused prep: block 0 = exclusive scan of degc; block 1 = BN fold (both layers);
//      blocks 2..193 = wbig pack (both layers). All depend only on k_momdeg.
__global__ void k_prep(const int* __restrict__ degc, int* __restrict__ row_start,
                       const float* __restrict__ mop,
                       const float* __restrict__ w1_0, const float* __restrict__ b1_0,
                       const float* __restrict__ g_0, const float* __restrict__ be_0,
                       const float* __restrict__ w1_1, const float* __restrict__ b1_1,
                       const float* __restrict__ g_1, const float* __restrict__ be_1,
                       float* __restrict__ w1f0, float* __restrict__ b1f0,
                       float* __restrict__ w1f1, float* __restrict__ b1f1,
                       const float* __restrict__ w2_0, const float* __restrict__ b2_0,
                       const float* __restrict__ w2_1, const float* __restrict__ b2_1,
                       float* __restrict__ wb0, float* __restrict__ wb1) {
    int b = blockIdx.x, t = threadIdx.x;
    if (b == 0) {
        __shared__ int p[256];
        const int CHUNK = 40;                 // 250*40 == 10000 exactly
        int base = t * CHUNK;
        int sum = 0;
        if (t < 250) {
            for (int i = 0; i < CHUNK; i++) sum += degc[base + i];
        }
        p[t] = sum;
        __syncthreads();
        for (int off = 1; off < 256; off <<= 1) {
            int v = (t >= off) ? p[t - off] : 0;
            __syncthreads();
            p[t] += v;
            __syncthreads();
        }
        int excl = p[t] - sum;
        if (t < 250) {
            int run = excl;
            for (int i = 0; i < CHUNK; i++) {
                row_start[base + i] = run;
                run += degc[base + i];
            }
        }
        if (t == 0) row_start[NN] = EE;
    } else if (b == 1) {
        __shared__ float mo[9];
        if (t < 9) {
            float s = 0.f;
            for (int bb = 0; bb < 128; bb++) s += mop[bb * 12 + t];
            mo[t] = s;
        }
        __syncthreads();
        int grp = t >> 5, j = t & 31;
        if (grp < 2 && j < HIDK) {
            const float* w1 = grp ? w1_1 : w1_0;
            const float* b1 = grp ? b1_1 : b1_0;
            const float* g  = grp ? g_1  : g_0;
            const float* be = grp ? be_1 : be_0;
            float* w1f = grp ? w1f1 : w1f0;
            float* b1f = grp ? b1f1 : b1f0;
            const float inv = 1.0f / (float)EE;
            float m0 = mo[0] * inv, m1 = mo[1] * inv, m2 = mo[2] * inv;
            float c00 = mo[3] * inv - m0 * m0, c01 = mo[4] * inv - m0 * m1, c02 = mo[5] * inv - m0 * m2;
            float c11 = mo[6] * inv - m1 * m1, c12 = mo[7] * inv - m1 * m2, c22 = mo[8] * inv - m2 * m2;
            float w0 = w1[j], wa = w1[25 + j], wb = w1[50 + j];
            float mean = m0 * w0 + m1 * wa + m2 * wb + b1[j];
            float var = w0 * w0 * c00 + wa * wa * c11 + wb * wb * c22
                      + 2.f * (w0 * wa * c01 + w0 * wb * c02 + wa * wb * c12);
            float sc = g[j] * rsqrtf(var + EPSBN);
            w1f[j] = w0 * sc; w1f[25 + j] = wa * sc; w1f[50 + j] = wb * sc;
            b1f[j] = (b1[j] - mean) * sc + be[j];
        }
    } else {
        int idx = (b - 2) * 256 + t;
        if (idx < KROWS * 16 * DOUT) wpack<16>(idx, w2_0, b2_0, wb0);
        else if (idx < KROWS * 16 * DOUT + KROWS * 32 * DOUT)
            wpack<32>(idx - KROWS * 16 * DOUT, w2_1, b2_1, wb1);
    }
}

// ---- scatter edges into CSR slots; ALSO pre-gather edge_attr into slot order
__global__ void k_scatter(const int* __restrict__ ei, const float* __restrict__ ea,
                          const int* __restrict__ row_start,
                          int* __restrict__ cur, int* __restrict__ csr_src,
                          float* __restrict__ eacsr) {
    int e = blockIdx.x * blockDim.x + threadIdx.x;
    if (e >= EE) return;
    int d = ei[EE + e];
    int pos = atomicAdd(cur + d, 1);
    int idx = row_start[d] + pos;
    csr_src[idx] = ei[e];
    float4 av = { ea[3 * e], ea[3 * e + 1], ea[3 * e + 2], 0.f };
    *(float4*)(eacsr + 4 * (size_t)idx) = av;
}

// ---- FUSED layer kernel. TWO waves per node (edge-parity split), block = 2 nodes.
// Software-pipelined Phase A: indices 2 iters ahead, x/ea 1-2 iters ahead,
// h double-buffered in LDS (hv for iter n+1 computed+written during iter n;
// ds_reads issued BEFORE the ds_write so the in-order DS queue never stalls reads).
// Phase B: each wave covers 8 k-rows for BOTH nodes (half-waves split i4 range)
// -> each wbig float4 loaded once per block (halved L2 traffic).
// FINAL=true: epilogue atomicAdds into gsum (global mean pool), no xout store.
template <int DIN, int KPL, bool FINAL>
__global__ __launch_bounds__(256, 8)
void k_fused(const int* __restrict__ row_start,
             const int* __restrict__ csr_src,
             const float* __restrict__ eacsr,
             const float* __restrict__ w1f, const float* __restrict__ b1f,
             const float* __restrict__ wbig, const float* __restrict__ xin,
             const float* __restrict__ wr, const float* __restrict__ bc,
             const int* __restrict__ batch,
             float* __restrict__ xout, float* __restrict__ gsum) {
    __shared__ __align__(16) float Slds[4][KROWS][DIN];
    __shared__ float Olds[2][4][DOUT];
    __shared__ __align__(16) float hb[4][2][2][32];   // wave, buf, half, k
    int t = threadIdx.x;
    int w = t >> 6, lane = t & 63;
    int ln = w >> 1, q = w & 1;
    int n = blockIdx.x * 2 + ln;           // grid 5000 -> n in [0,10000)
    int start = row_start[n], end = row_start[n + 1];

    int il = lane & (DIN - 1);
    int kh = lane / DIN;                   // 64/DIN k-groups
    int kme = lane & 31;                   // which h-row this lane computes
    int half = lane >> 5;                  // 0: edge A, 1: edge B

    // per-lane folded edge-MLP coefficients (loop-invariant)
    float c0 = 0.f, c1 = 0.f, c2 = 0.f, c3 = 0.f;
    if (kme < HIDK) {
        c0 = w1f[kme]; c1 = w1f[25 + kme]; c2 = w1f[50 + kme]; c3 = b1f[kme];
    } else if (kme == HIDK) {
        c3 = 1.0f;                         // bias row: relu(1) == 1
    }

    float s[KPL];
#pragma unroll
    for (int j = 0; j < KPL; j++) s[j] = 0.f;

    const float4* ea4 = (const float4*)eacsr;

    // ---- Phase A (software-pipelined) ----
    int p = start + q;
    int sA0 = 0, sB0 = 0, vB0 = 0;             // indices/valid for p
    int sA1 = 0, sB1 = 0, vB1 = 0;             // indices/valid for p+4
    float xA = 0.f, xB = 0.f;                  // x values for p
    float4 av1 = {0.f, 0.f, 0.f, 0.f};         // edge-attrs for p+4 (this half's edge)
    int buf = 0;

    if (p < end) {
        int qB = p + 2; vB0 = (qB < end); int qBs0 = vB0 ? qB : p;
        sA0 = csr_src[p]; sB0 = csr_src[qBs0];
        int p1 = p + 4;
        int qBs1 = 0;
        if (p1 < end) {
            int qB1 = p1 + 2; vB1 = (qB1 < end); qBs1 = vB1 ? qB1 : p1;
            sA1 = csr_src[p1]; sB1 = csr_src[qBs1];
        }
        float4 av0 = ea4[half ? qBs0 : p];
        xA = xin[sA0 * DIN + il];
        xB = xin[sB0 * DIN + il];
        if (p1 < end) av1 = ea4[half ? qBs1 : p1];
        float hv = av0.x * c0 + av0.y * c1 + av0.z * c2 + c3;
        hv = hv > 0.f ? hv : 0.f;
        hb[w][0][half][kme] = hv;
    }
    while (p < end) {
        int p1 = p + 4, p2 = p + 8;
        // prefetch indices for p2 and edge-attrs for p2 (no index dependency)
        int sA2 = 0, sB2 = 0, vB2 = 0;
        float4 av2 = {0.f, 0.f, 0.f, 0.f};
        if (p2 < end) {
            int qB2 = p2 + 2; vB2 = (qB2 < end); int qBs2 = vB2 ? qB2 : p2;
            sA2 = csr_src[p2]; sB2 = csr_src[qBs2];
            av2 = ea4[half ? qBs2 : p2];
        }
        // prefetch x for p1 (indices loaded last iteration)
        float xAn = 0.f, xBn = 0.f;
        if (p1 < end) { xAn = xin[sA1 * DIN + il]; xBn = xin[sB1 * DIN + il]; }
        // read current h (written last iteration / prologue) BEFORE this iter's write
        const float4* hA4 = (const float4*)&hb[w][buf][0][kh * KPL];
        const float4* hB4 = (const float4*)&hb[w][buf][1][kh * KPL];
        float4 ha[KPL / 4], hbv[KPL / 4];
#pragma unroll
        for (int j4 = 0; j4 < KPL / 4; j4++) { ha[j4] = hA4[j4]; hbv[j4] = hB4[j4]; }
        // write next iteration's h (av1 arrived: issued >= 1 iteration ago)
        if (p1 < end) {
            float hv = av1.x * c0 + av1.y * c1 + av1.z * c2 + c3;
            hv = hv > 0.f ? hv : 0.f;
            hb[w][buf ^ 1][half][kme] = hv;
        }
        // FMA
        float xBm = vB0 ? xB : 0.f;
#pragma unroll
        for (int j4 = 0; j4 < KPL / 4; j4++) {
            s[j4 * 4 + 0] += ha[j4].x * xA; s[j4 * 4 + 1] += ha[j4].y * xA;
            s[j4 * 4 + 2] += ha[j4].z * xA; s[j4 * 4 + 3] += ha[j4].w * xA;
        }
#pragma unroll
        for (int j4 = 0; j4 < KPL / 4; j4++) {
            s[j4 * 4 + 0] += hbv[j4].x * xBm; s[j4 * 4 + 1] += hbv[j4].y * xBm;
            s[j4 * 4 + 2] += hbv[j4].z * xBm; s[j4 * 4 + 3] += hbv[j4].w * xBm;
        }
        // rotate pipeline state
        p = p1;
        sA0 = sA1; sB0 = sB1; vB0 = vB1;
        sA1 = sA2; sB1 = sB2; vB1 = vB2;
        xA = xAn; xB = xBn; av1 = av2;
        buf ^= 1;
    }
#pragma unroll
    for (int j = 0; j < KPL; j++)
        Slds[w][kh * KPL + j][il] = s[j];
    __syncthreads();

    // ---- parity pre-sum: Slds[2*node] += Slds[2*node+1] (once, cooperatively) ----
    constexpr int PER = KROWS * DIN / 4;    // float4s per buffer
    for (int f = t; f < 2 * PER; f += 256) {
        int node = f / PER, rem = f - node * PER;
        float4* dst = (float4*)&Slds[2 * node][0][0];
        const float4* sp = (const float4*)&Slds[2 * node + 1][0][0];
        float4 a = dst[rem], b = sp[rem];
        a.x += b.x; a.y += b.y; a.z += b.z; a.w += b.w;
        dst[rem] = a;
    }
    __syncthreads();

    // ---- Phase B: wave w covers k-rows [w*8, w*8+8) for BOTH nodes;
    //      half-waves split the i4 range; wbig read once per block.
    {
        int o = lane & 31, hf = lane >> 5;
        constexpr int I4H = DIN / 8;        // i4 per half-wave
        const float4* wb4 = (const float4*)wbig;
        float acc0 = 0.f, acc1 = 0.f;
        int kbase = w * (KROWS / 4);
#pragma unroll
        for (int kk = 0; kk < KROWS / 4; kk++) {
            int k = kbase + kk;
#pragma unroll
            for (int j = 0; j < I4H; j++) {
                int i4 = hf * I4H + j;
                float4 wv = wb4[(k * (DIN / 4) + i4) * 32 + o];
                float4 s0 = *(const float4*)&Slds[0][k][i4 * 4];
                float4 s1 = *(const float4*)&Slds[2][k][i4 * 4];
                acc0 += s0.x * wv.x + s0.y * wv.y + s0.z * wv.z + s0.w * wv.w;
                acc1 += s1.x * wv.x + s1.y * wv.y + s1.z * wv.z + s1.w * wv.w;
            }
        }
        acc0 += __shfl_xor(acc0, 32);       // combine i4 halves
        acc1 += __shfl_xor(acc1, 32);
        if (hf == 0) { Olds[0][w][o] = acc0; Olds[1][w][o] = acc1; }
    }
    __syncthreads();

    // ---- finalize (wave 0: 2 nodes x 32 lanes) ----
    if (t < 64) {
        int ln2 = t >> 5, o2 = t & 31;
        int n2 = blockIdx.x * 2 + ln2;
        int cnt2 = row_start[n2 + 1] - row_start[n2];
        float d = (float)cnt2; if (d < 1.f) d = 1.f;
        float agg = Olds[ln2][0][o2] + Olds[ln2][1][o2]
                  + Olds[ln2][2][o2] + Olds[ln2][3][o2];
        float r = agg / d + bc[o2];
#pragma unroll
        for (int i = 0; i < DIN; i++) r += xin[n2 * DIN + i] * wr[i * DOUT + o2];
        r = r > 0.f ? r : expm1f(r);
        if (FINAL) atomicAdd(gsum + batch[n2] * DOUT + o2, r);
        else xout[n2 * DOUT + o2] = r;
    }
}

// ---- final fc; per-graph node counts via binary search on SORTED batch
__global__ void k_fc(const float* __restrict__ gsum, const int* __restrict__ batch,
                     const float* __restrict__ wfc, const float* __restrict__ bfc,
                     float* __restrict__ out) {
    int g = threadIdx.x;
    if (g >= GG) return;
    int lo = 0, hi = NN;
    while (lo < hi) { int mid = (lo + hi) >> 1; if (batch[mid] < g) lo = mid + 1; else hi = mid; }
    int lb = lo;
    lo = 0; hi = NN;
    while (lo < hi) { int mid = (lo + hi) >> 1; if (batch[mid] < g + 1) lo = mid + 1; else hi = mid; }
    float c = (float)(lo - lb); if (c < 1.f) c = 1.f;
    float acc = 0.f;
#pragma unroll
    for (int o = 0; o < DOUT; o++) acc += gsum[g * DOUT + o] * wfc[o];
    out[g] = acc / c + bfc[0];
}

extern "C" void kernel_launch(void* const* d_in, const int* in_sizes, int n_in,
                              void* d_out, int out_size, void* d_ws, size_t ws_size,
                              hipStream_t stream) {
    const float* x     = (const float*)d_in[0];
    const float* ea    = (const float*)d_in[1];
    const int*   ei    = (const int*)d_in[2];
    const int*   batch = (const int*)d_in[3];
    const float* w1_0 = (const float*)d_in[4];
    const float* b1_0 = (const float*)d_in[5];
    const float* g_0  = (const float*)d_in[6];
    const float* be_0 = (const float*)d_in[7];
    const float* w2_0 = (const float*)d_in[8];
    const float* b2_0 = (const float*)d_in[9];
    const float* wr_0 = (const float*)d_in[10];
    const float* bc_0 = (const float*)d_in[11];
    const float* w1_1 = (const float*)d_in[12];
    const float* b1_1 = (const float*)d_in[13];
    const float* g_1  = (const float*)d_in[14];
    const float* be_1 = (const float*)d_in[15];
    const float* w2_1 = (const float*)d_in[16];
    const float* b2_1 = (const float*)d_in[17];
    const float* wr_1 = (const float*)d_in[18];
    const float* bc_1 = (const float*)d_in[19];
    const float* wfc  = (const float*)d_in[20];
    const float* bfc  = (const float*)d_in[21];

    float* ws    = (float*)d_ws;
    int*   cur   = (int*)(ws + OFF_CUR);
    float* gsum  = ws + OFF_GSUM;
    int*   degc  = (int*)(ws + OFF_DEGC);
    float* mop   = ws + OFF_MOP;
    float* w1f0  = ws + OFF_W1F0;
    float* b1f0  = ws + OFF_B1F0;
    float* w1f1  = ws + OFF_W1F1;
    float* b1f1  = ws + OFF_B1F1;
    int*   row   = (int*)(ws + OFF_ROW);
    int*   csrc  = (int*)(ws + OFF_SRC);
    float* eacsr = ws + OFF_EA;
    float* wb0   = ws + OFF_WB0;
    float* wb1   = ws + OFF_WB1;
    float* x1    = ws + OFF_X1;

    hipMemsetAsync(ws, 0, (size_t)ZERO_FLOATS * sizeof(float), stream);

    k_momdeg<<<128, 256, 0, stream>>>(ea, ei, mop, degc);
    k_prep<<<194, 256, 0, stream>>>(degc, row, mop,
                                    w1_0, b1_0, g_0, be_0, w1_1, b1_1, g_1, be_1,
                                    w1f0, b1f0, w1f1, b1f1,
                                    w2_0, b2_0, w2_1, b2_1, wb0, wb1);
    k_scatter<<<(EE + 255) / 256, 256, 0, stream>>>(ei, ea, row, cur, csrc, eacsr);

    // ---- layer 0 (din=16), h fused in
    k_fused<16, 8, false><<<NN / 2, 256, 0, stream>>>(row, csrc, eacsr, w1f0, b1f0,
                                                      wb0, x, wr_0, bc_0, batch, x1, gsum);
    // ---- layer 1 (din=32), fused global-mean-pool epilogue
    k_fused<32, 16, true><<<NN / 2, 256, 0, stream>>>(row, csrc, eacsr, w1f1, b1f1,
                                                      wb1, x1, wr_1, bc_1, batch, nullptr, gsum);

    // ---- fc (counts via binary search on sorted batch)
    k_fc<<<1, 128, 0, stream>>>(gsum, batch, wfc, bfc, (float*)d_out);
}

// Round 4
// 211.704 us; speedup vs baseline: 1.1992x; 1.1992x over previous
//
#include <hip/hip_runtime.h>
#include <math.h>

// Problem constants (fixed by reference)
#define NN   10000
#define EE   160000
#define GG   128
#define HIDK 25
#define KROWS 32     // 25 MLP rows + 1 b2 row (k=25) + 6 zero-pad rows
#define DOUT 32
#define EPSBN 1e-5f

// ---------------- workspace layout (float offsets) ----------------
// zeroed region (one hipMemsetAsync):
#define OFF_CUR   0          // NN ints (scatter cursors), pad 10016
#define OFF_GSUM  10016      // G*32 = 4096
#define OFF_DEGC  14112      // NN ints, pad 10016
#define ZERO_FLOATS 24128
// non-zeroed:
#define OFF_MOP   24128      // 128*12 moment partials
#define OFF_W1F0  25664      // 80
#define OFF_B1F0  25744      // 32
#define OFF_W1F1  25776      // 80
#define OFF_B1F1  25856      // 32
#define OFF_ROW   25888      // NN+1 ints, pad 10016
#define OFF_SRC   35904      // E ints (csr src nodes)
#define OFF_EA    195904     // E*4 floats: edge_attr gathered into CSR slot order (float4-padded)
#define OFF_WB0   835904     // 32*16*32 = 16384
#define OFF_WB1   852288     // 32*32*32 = 32768
#define OFF_X1    885056     // N*32
#define TOTAL_FLOATS 1205056 // ~4.8 MB of d_ws

__device__ inline float wave_red(float v) {
    for (int off = 32; off; off >>= 1) v += __shfl_down(v, off);
    return v;
}

// ---- moments partials (128 blocks, atomic-free) + in-degree atomics, one pass
__global__ void k_momdeg(const float* __restrict__ ea, const int* __restrict__ ei,
                         float* __restrict__ mop, int* __restrict__ degc) {
    __shared__ float ls[4][9];
    float s[9];
#pragma unroll
    for (int j = 0; j < 9; j++) s[j] = 0.f;
    int t = threadIdx.x;
    for (int e = blockIdx.x * 256 + t; e < EE; e += 128 * 256) {
        float a0 = ea[3 * e], a1 = ea[3 * e + 1], a2 = ea[3 * e + 2];
        s[0] += a0; s[1] += a1; s[2] += a2;
        s[3] += a0 * a0; s[4] += a0 * a1; s[5] += a0 * a2;
        s[6] += a1 * a1; s[7] += a1 * a2; s[8] += a2 * a2;
        atomicAdd(degc + ei[EE + e], 1);
    }
    int w = t >> 6, lane = t & 63;
#pragma unroll
    for (int j = 0; j < 9; j++) {
        float r = wave_red(s[j]);
        if (lane == 0) ls[w][j] = r;
    }
    __syncthreads();
    if (t < 9) mop[blockIdx.x * 12 + t] = ls[0][t] + ls[1][t] + ls[2][t] + ls[3][t];
}

// ---- pack wbig[k][i4][o][c] = w2[k][i4*4+c][o]; row 25 = b2; rows >= 26 = 0
template <int DIN>
__device__ inline void wpack(int idx, const float* __restrict__ w2,
                             const float* __restrict__ b2, float* __restrict__ wbig) {
    int k = idx / (DIN * DOUT);
    int rem = idx - k * (DIN * DOUT);
    int i4 = rem / (4 * DOUT);
    int rem2 = rem - i4 * (4 * DOUT);
    int o = rem2 >> 2, c = rem2 & 3;
    int i = i4 * 4 + c;
    float v = 0.f;
    if (k < HIDK) v = w2[(k * DIN + i) * DOUT + o];
    else if (k == HIDK) v = b2[i * DOUT + o];
    wbig[idx] = v;
}

// ---- fused prep: block 0 = exclusive scan of degc; block 1 = BN fold (both layers);
//      blocks 2..193 = wbig pack (both layers). All depend only on k_momdeg.
__global__ void k_prep(const int* __restrict__ degc, int* __restrict__ row_start,
                       const float* __restrict__ mop,
                       const float* __restrict__ w1_0, const float* __restrict__ b1_0,
                       const float* __restrict__ g_0, const float* __restrict__ be_0,
                       const float* __restrict__ w1_1, const float* __restrict__ b1_1,
                       const float* __restrict__ g_1, const float* __restrict__ be_1,
                       float* __restrict__ w1f0, float* __restrict__ b1f0,
                       float* __restrict__ w1f1, float* __restrict__ b1f1,
                       const float* __restrict__ w2_0, const float* __restrict__ b2_0,
                       const float* __restrict__ w2_1, const float* __restrict__ b2_1,
                       float* __restrict__ wb0, float* __restrict__ wb1) {
    int b = blockIdx.x, t = threadIdx.x;
    if (b == 0) {
        __shared__ int p[256];
        const int CHUNK = 40;                 // 250*40 == 10000 exactly
        int base = t * CHUNK;
        int sum = 0;
        if (t < 250) {
            for (int i = 0; i < CHUNK; i++) sum += degc[base + i];
        }
        p[t] = sum;
        __syncthreads();
        for (int off = 1; off < 256; off <<= 1) {
            int v = (t >= off) ? p[t - off] : 0;
            __syncthreads();
            p[t] += v;
            __syncthreads();
        }
        int excl = p[t] - sum;
        if (t < 250) {
            int run = excl;
            for (int i = 0; i < CHUNK; i++) {
                row_start[base + i] = run;
                run += degc[base + i];
            }
        }
        if (t == 0) row_start[NN] = EE;
    } else if (b == 1) {
        __shared__ float mo[9];
        if (t < 9) {
            float s = 0.f;
            for (int bb = 0; bb < 128; bb++) s += mop[bb * 12 + t];
            mo[t] = s;
        }
        __syncthreads();
        int grp = t >> 5, j = t & 31;
        if (grp < 2 && j < HIDK) {
            const float* w1 = grp ? w1_1 : w1_0;
            const float* b1 = grp ? b1_1 : b1_0;
            const float* g  = grp ? g_1  : g_0;
            const float* be = grp ? be_1 : be_0;
            float* w1f = grp ? w1f1 : w1f0;
            float* b1f = grp ? b1f1 : b1f0;
            const float inv = 1.0f / (float)EE;
            float m0 = mo[0] * inv, m1 = mo[1] * inv, m2 = mo[2] * inv;
            float c00 = mo[3] * inv - m0 * m0, c01 = mo[4] * inv - m0 * m1, c02 = mo[5] * inv - m0 * m2;
            float c11 = mo[6] * inv - m1 * m1, c12 = mo[7] * inv - m1 * m2, c22 = mo[8] * inv - m2 * m2;
            float w0 = w1[j], wa = w1[25 + j], wb = w1[50 + j];
            float mean = m0 * w0 + m1 * wa + m2 * wb + b1[j];
            float var = w0 * w0 * c00 + wa * wa * c11 + wb * wb * c22
                      + 2.f * (w0 * wa * c01 + w0 * wb * c02 + wa * wb * c12);
            float sc = g[j] * rsqrtf(var + EPSBN);
            w1f[j] = w0 * sc; w1f[25 + j] = wa * sc; w1f[50 + j] = wb * sc;
            b1f[j] = (b1[j] - mean) * sc + be[j];
        }
    } else {
        int idx = (b - 2) * 256 + t;
        if (idx < KROWS * 16 * DOUT) wpack<16>(idx, w2_0, b2_0, wb0);
        else if (idx < KROWS * 16 * DOUT + KROWS * 32 * DOUT)
            wpack<32>(idx - KROWS * 16 * DOUT, w2_1, b2_1, wb1);
    }
}

// ---- scatter edges into CSR slots; ALSO pre-gather edge_attr into slot order
__global__ void k_scatter(const int* __restrict__ ei, const float* __restrict__ ea,
                          const int* __restrict__ row_start,
                          int* __restrict__ cur, int* __restrict__ csr_src,
                          float* __restrict__ eacsr) {
    int e = blockIdx.x * blockDim.x + threadIdx.x;
    if (e >= EE) return;
    int d = ei[EE + e];
    int pos = atomicAdd(cur + d, 1);
    int idx = row_start[d] + pos;
    csr_src[idx] = ei[e];
    float4 av = { ea[3 * e], ea[3 * e + 1], ea[3 * e + 2], 0.f };
    *(float4*)(eacsr + 4 * (size_t)idx) = av;
}

// ---- FUSED layer kernel. TWO waves per node (edge-parity split), block = 2 nodes.
// Software-pipelined Phase A: indices 2 iters ahead, x/ea 1-2 iters ahead,
// h double-buffered in LDS. MINW=6 (NOT 8): the pipeline state needs ~70-85 VGPRs;
// capping at 64 (MINW=8) made the compiler spill the hot loop to scratch
// (R3: WRITE_SIZE 1.9->185 MB, 103 us). 6 blocks/CU = 75% occupancy, no spill.
// Phase B: each wave covers 8 k-rows for BOTH nodes (half-waves split i4 range).
// FINAL=true: epilogue atomicAdds into gsum (global mean pool), no xout store.
template <int DIN, int KPL, bool FINAL, int MINW>
__global__ __launch_bounds__(256, MINW)
void k_fused(const int* __restrict__ row_start,
             const int* __restrict__ csr_src,
             const float* __restrict__ eacsr,
             const float* __restrict__ w1f, const float* __restrict__ b1f,
             const float* __restrict__ wbig, const float* __restrict__ xin,
             const float* __restrict__ wr, const float* __restrict__ bc,
             const int* __restrict__ batch,
             float* __restrict__ xout, float* __restrict__ gsum) {
    __shared__ __align__(16) float Slds[4][KROWS][DIN];
    __shared__ float Olds[2][4][DOUT];
    __shared__ __align__(16) float hb[4][2][2][32];   // wave, buf, half, k
    int t = threadIdx.x;
    int w = t >> 6, lane = t & 63;
    int ln = w >> 1, q = w & 1;
    int n = blockIdx.x * 2 + ln;           // grid 5000 -> n in [0,10000)
    int start = row_start[n], end = row_start[n + 1];

    int il = lane & (DIN - 1);
    int kh = lane / DIN;                   // 64/DIN k-groups
    int kme = lane & 31;                   // which h-row this lane computes
    int half = lane >> 5;                  // 0: edge A, 1: edge B

    // per-lane folded edge-MLP coefficients (loop-invariant)
    float c0 = 0.f, c1 = 0.f, c2 = 0.f, c3 = 0.f;
    if (kme < HIDK) {
        c0 = w1f[kme]; c1 = w1f[25 + kme]; c2 = w1f[50 + kme]; c3 = b1f[kme];
    } else if (kme == HIDK) {
        c3 = 1.0f;                         // bias row: relu(1) == 1
    }

    float s[KPL];
#pragma unroll
    for (int j = 0; j < KPL; j++) s[j] = 0.f;

    const float4* ea4 = (const float4*)eacsr;

    // ---- Phase A (software-pipelined) ----
    int p = start + q;
    int sA0 = 0, sB0 = 0, vB0 = 0;             // indices/valid for p
    int sA1 = 0, sB1 = 0, vB1 = 0;             // indices/valid for p+4
    float xA = 0.f, xB = 0.f;                  // x values for p
    float4 av1 = {0.f, 0.f, 0.f, 0.f};         // edge-attrs for p+4 (this half's edge)
    int buf = 0;

    if (p < end) {
        int qB = p + 2; vB0 = (qB < end); int qBs0 = vB0 ? qB : p;
        sA0 = csr_src[p]; sB0 = csr_src[qBs0];
        int p1 = p + 4;
        int qBs1 = 0;
        if (p1 < end) {
            int qB1 = p1 + 2; vB1 = (qB1 < end); qBs1 = vB1 ? qB1 : p1;
            sA1 = csr_src[p1]; sB1 = csr_src[qBs1];
        }
        float4 av0 = ea4[half ? qBs0 : p];
        xA = xin[sA0 * DIN + il];
        xB = xin[sB0 * DIN + il];
        if (p1 < end) av1 = ea4[half ? qBs1 : p1];
        float hv = av0.x * c0 + av0.y * c1 + av0.z * c2 + c3;
        hv = hv > 0.f ? hv : 0.f;
        hb[w][0][half][kme] = hv;
    }
    while (p < end) {
        int p1 = p + 4, p2 = p + 8;
        // prefetch indices for p2 and edge-attrs for p2 (no index dependency)
        int sA2 = 0, sB2 = 0, vB2 = 0;
        float4 av2 = {0.f, 0.f, 0.f, 0.f};
        if (p2 < end) {
            int qB2 = p2 + 2; vB2 = (qB2 < end); int qBs2 = vB2 ? qB2 : p2;
            sA2 = csr_src[p2]; sB2 = csr_src[qBs2];
            av2 = ea4[half ? qBs2 : p2];
        }
        // prefetch x for p1 (indices loaded last iteration)
        float xAn = 0.f, xBn = 0.f;
        if (p1 < end) { xAn = xin[sA1 * DIN + il]; xBn = xin[sB1 * DIN + il]; }
        // read current h (written last iteration / prologue) BEFORE this iter's write
        const float4* hA4 = (const float4*)&hb[w][buf][0][kh * KPL];
        const float4* hB4 = (const float4*)&hb[w][buf][1][kh * KPL];
        float4 ha[KPL / 4], hbv[KPL / 4];
#pragma unroll
        for (int j4 = 0; j4 < KPL / 4; j4++) { ha[j4] = hA4[j4]; hbv[j4] = hB4[j4]; }
        // write next iteration's h (av1 arrived: issued >= 1 iteration ago)
        if (p1 < end) {
            float hv = av1.x * c0 + av1.y * c1 + av1.z * c2 + c3;
            hv = hv > 0.f ? hv : 0.f;
            hb[w][buf ^ 1][half][kme] = hv;
        }
        // FMA
        float xBm = vB0 ? xB : 0.f;
#pragma unroll
        for (int j4 = 0; j4 < KPL / 4; j4++) {
            s[j4 * 4 + 0] += ha[j4].x * xA; s[j4 * 4 + 1] += ha[j4].y * xA;
            s[j4 * 4 + 2] += ha[j4].z * xA; s[j4 * 4 + 3] += ha[j4].w * xA;
        }
#pragma unroll
        for (int j4 = 0; j4 < KPL / 4; j4++) {
            s[j4 * 4 + 0] += hbv[j4].x * xBm; s[j4 * 4 + 1] += hbv[j4].y * xBm;
            s[j4 * 4 + 2] += hbv[j4].z * xBm; s[j4 * 4 + 3] += hbv[j4].w * xBm;
        }
        // rotate pipeline state
        p = p1;
        sA0 = sA1; sB0 = sB1; vB0 = vB1;
        sA1 = sA2; sB1 = sB2; vB1 = vB2;
        xA = xAn; xB = xBn; av1 = av2;
        buf ^= 1;
    }
#pragma unroll
    for (int j = 0; j < KPL; j++)
        Slds[w][kh * KPL + j][il] = s[j];
    __syncthreads();

    // ---- parity pre-sum: Slds[2*node] += Slds[2*node+1] (once, cooperatively) ----
    constexpr int PER = KROWS * DIN / 4;    // float4s per buffer
    for (int f = t; f < 2 * PER; f += 256) {
        int node = f / PER, rem = f - node * PER;
        float4* dst = (float4*)&Slds[2 * node][0][0];
        const float4* sp = (const float4*)&Slds[2 * node + 1][0][0];
        float4 a = dst[rem], b = sp[rem];
        a.x += b.x; a.y += b.y; a.z += b.z; a.w += b.w;
        dst[rem] = a;
    }
    __syncthreads();

    // ---- Phase B: wave w covers k-rows [w*8, w*8+8) for BOTH nodes;
    //      half-waves split the i4 range; wbig read once per block.
    {
        int o = lane & 31, hf = lane >> 5;
        constexpr int I4H = DIN / 8;        // i4 per half-wave
        const float4* wb4 = (const float4*)wbig;
        float acc0 = 0.f, acc1 = 0.f;
        int kbase = w * (KROWS / 4);
#pragma unroll
        for (int kk = 0; kk < KROWS / 4; kk++) {
            int k = kbase + kk;
#pragma unroll
            for (int j = 0; j < I4H; j++) {
                int i4 = hf * I4H + j;
                float4 wv = wb4[(k * (DIN / 4) + i4) * 32 + o];
                float4 s0 = *(const float4*)&Slds[0][k][i4 * 4];
                float4 s1 = *(const float4*)&Slds[2][k][i4 * 4];
                acc0 += s0.x * wv.x + s0.y * wv.y + s0.z * wv.z + s0.w * wv.w;
                acc1 += s1.x * wv.x + s1.y * wv.y + s1.z * wv.z + s1.w * wv.w;
            }
        }
        acc0 += __shfl_xor(acc0, 32);       // combine i4 halves
        acc1 += __shfl_xor(acc1, 32);
        if (hf == 0) { Olds[0][w][o] = acc0; Olds[1][w][o] = acc1; }
    }
    __syncthreads();

    // ---- finalize (wave 0: 2 nodes x 32 lanes) ----
    if (t < 64) {
        int ln2 = t >> 5, o2 = t & 31;
        int n2 = blockIdx.x * 2 + ln2;
        int cnt2 = row_start[n2 + 1] - row_start[n2];
        float d = (float)cnt2; if (d < 1.f) d = 1.f;
        float agg = Olds[ln2][0][o2] + Olds[ln2][1][o2]
                  + Olds[ln2][2][o2] + Olds[ln2][3][o2];
        float r = agg / d + bc[o2];
#pragma unroll
        for (int i = 0; i < DIN; i++) r += xin[n2 * DIN + i] * wr[i * DOUT + o2];
        r = r > 0.f ? r : expm1f(r);
        if (FINAL) atomicAdd(gsum + batch[n2] * DOUT + o2, r);
        else xout[n2 * DOUT + o2] = r;
    }
}

// ---- final fc; per-graph node counts via binary search on SORTED batch
__global__ void k_fc(const float* __restrict__ gsum, const int* __restrict__ batch,
                     const float* __restrict__ wfc, const float* __restrict__ bfc,
                     float* __restrict__ out) {
    int g = threadIdx.x;
    if (g >= GG) return;
    int lo = 0, hi = NN;
    while (lo < hi) { int mid = (lo + hi) >> 1; if (batch[mid] < g) lo = mid + 1; else hi = mid; }
    int lb = lo;
    lo = 0; hi = NN;
    while (lo < hi) { int mid = (lo + hi) >> 1; if (batch[mid] < g + 1) lo = mid + 1; else hi = mid; }
    float c = (float)(lo - lb); if (c < 1.f) c = 1.f;
    float acc = 0.f;
#pragma unroll
    for (int o = 0; o < DOUT; o++) acc += gsum[g * DOUT + o] * wfc[o];
    out[g] = acc / c + bfc[0];
}

extern "C" void kernel_launch(void* const* d_in, const int* in_sizes, int n_in,
                              void* d_out, int out_size, void* d_ws, size_t ws_size,
                              hipStream_t stream) {
    const float* x     = (const float*)d_in[0];
    const float* ea    = (const float*)d_in[1];
    const int*   ei    = (const int*)d_in[2];
    const int*   batch = (const int*)d_in[3];
    const float* w1_0 = (const float*)d_in[4];
    const float* b1_0 = (const float*)d_in[5];
    const float* g_0  = (const float*)d_in[6];
    const float* be_0 = (const float*)d_in[7];
    const float* w2_0 = (const float*)d_in[8];
    const float* b2_0 = (const float*)d_in[9];
    const float* wr_0 = (const float*)d_in[10];
    const float* bc_0 = (const float*)d_in[11];
    const float* w1_1 = (const float*)d_in[12];
    const float* b1_1 = (const float*)d_in[13];
    const float* g_1  = (const float*)d_in[14];
    const float* be_1 = (const float*)d_in[15];
    const float* w2_1 = (const float*)d_in[16];
    const float* b2_1 = (const float*)d_in[17];
    const float* wr_1 = (const float*)d_in[18];
    const float* bc_1 = (const float*)d_in[19];
    const float* wfc  = (const float*)d_in[20];
    const float* bfc  = (const float*)d_in[21];

    float* ws    = (float*)d_ws;
    int*   cur   = (int*)(ws + OFF_CUR);
    float* gsum  = ws + OFF_GSUM;
    int*   degc  = (int*)(ws + OFF_DEGC);
    float* mop   = ws + OFF_MOP;
    float* w1f0  = ws + OFF_W1F0;
    float* b1f0  = ws + OFF_B1F0;
    float* w1f1  = ws + OFF_W1F1;
    float* b1f1  = ws + OFF_B1F1;
    int*   row   = (int*)(ws + OFF_ROW);
    int*   csrc  = (int*)(ws + OFF_SRC);
    float* eacsr = ws + OFF_EA;
    float* wb0   = ws + OFF_WB0;
    float* wb1   = ws + OFF_WB1;
    float* x1    = ws + OFF_X1;

    hipMemsetAsync(ws, 0, (size_t)ZERO_FLOATS * sizeof(float), stream);

    k_momdeg<<<128, 256, 0, stream>>>(ea, ei, mop, degc);
    k_prep<<<194, 256, 0, stream>>>(degc, row, mop,
                                    w1_0, b1_0, g_0, be_0, w1_1, b1_1, g_1, be_1,
                                    w1f0, b1f0, w1f1, b1f1,
                                    w2_0, b2_0, w2_1, b2_1, wb0, wb1);
    k_scatter<<<(EE + 255) / 256, 256, 0, stream>>>(ei, ea, row, cur, csrc, eacsr);

    // ---- layer 0 (din=16), h fused in
    k_fused<16, 8, false, 6><<<NN / 2, 256, 0, stream>>>(row, csrc, eacsr, w1f0, b1f0,
                                                         wb0, x, wr_0, bc_0, batch, x1, gsum);
    // ---- layer 1 (din=32), fused global-mean-pool epilogue
    k_fused<32, 16, true, 6><<<NN / 2, 256, 0, stream>>>(row, csrc, eacsr, w1f1, b1f1,
                                                         wb1, x1, wr_1, bc_1, batch, nullptr, gsum);

    // ---- fc (counts via binary search on sorted batch)
    k_fc<<<1, 128, 0, stream>>>(gsum, batch, wfc, bfc, (float*)d_out);
}